// Round 18
// baseline (1253.210 us; speedup 1.0000x reference)
//
#include <hip/hip_runtime.h>
#include <hip/hip_bf16.h>
#include <cstdint>

#define CDIM 512
#define NTOK 100352   // 2 * 16*56*56
#define LPB  50176    // tokens per batch
#define NTW  98       // tokens per window
#define QKVLD 1536
#define MLPDIM 2048

typedef __bf16 bf16x8 __attribute__((ext_vector_type(8)));
typedef float  f32x4  __attribute__((ext_vector_type(4)));

__device__ __forceinline__ float bf2f(unsigned short u) {
  union { unsigned int i; float f; } v; v.i = ((unsigned int)u) << 16; return v.f;
}
__device__ __forceinline__ unsigned short f2bf(float f) {
  union { float f; unsigned int i; } v; v.f = f;
  unsigned int u = v.i;
  return (unsigned short)((u + 0x7fffu + ((u >> 16) & 1u)) >> 16);
}
__device__ __forceinline__ unsigned cvtpk(float lo, float hi) {
  unsigned r;
  asm("v_cvt_pk_bf16_f32 %0, %1, %2" : "=v"(r) : "v"(lo), "v"(hi));
  return r;
}
__device__ __forceinline__ void unpack8(uint4 u, float* f) {
  f[0] = bf2f((unsigned short)(u.x & 0xffff)); f[1] = bf2f((unsigned short)(u.x >> 16));
  f[2] = bf2f((unsigned short)(u.y & 0xffff)); f[3] = bf2f((unsigned short)(u.y >> 16));
  f[4] = bf2f((unsigned short)(u.z & 0xffff)); f[5] = bf2f((unsigned short)(u.z >> 16));
  f[6] = bf2f((unsigned short)(u.w & 0xffff)); f[7] = bf2f((unsigned short)(u.w >> 16));
}
__device__ __forceinline__ uint4 pack8(const float* f) {
  uint4 u;
  u.x = (unsigned)f2bf(f[0]) | ((unsigned)f2bf(f[1]) << 16);
  u.y = (unsigned)f2bf(f[2]) | ((unsigned)f2bf(f[3]) << 16);
  u.z = (unsigned)f2bf(f[4]) | ((unsigned)f2bf(f[5]) << 16);
  u.w = (unsigned)f2bf(f[6]) | ((unsigned)f2bf(f[7]) << 16);
  return u;
}
__device__ __forceinline__ float gelu_f(float v) {
  float u = 0.7978845608028654f * (v + 0.044715f * v * v * v);
  float e = __expf(2.f * u);
  float t = 1.f - 2.f / (1.f + e);
  return 0.5f * v * (1.f + t);
}
__device__ __forceinline__ void gl2lds16(const unsigned short* g, unsigned short* l) {
  __builtin_amdgcn_global_load_lds((const __attribute__((address_space(1))) void*)g,
                                   (__attribute__((address_space(3))) void*)l, 16, 0, 0);
}

// ---------------- K0: weight fp32 KxN -> bf16 NxK (transpose + convert) ----------------
__global__ void cvt_t_kernel(const float* __restrict__ src, unsigned short* __restrict__ dst,
                             int lk, int N, int total) {
  int idx = blockIdx.x * 256 + threadIdx.x;
  if (idx >= total) return;
  int K = 1 << lk;
  int nn = idx >> lk, kk = idx & (K - 1);
  dst[idx] = f2bf(src[kk * N + nn]);
}

// ---------------- K1: LN1 + window partition, fp32 -> bf16 ----------------
__global__ __launch_bounds__(256) void ln1_kernel(const float* __restrict__ x,
    const float* __restrict__ g1, const float* __restrict__ b1,
    unsigned short* __restrict__ h) {
  int wid = threadIdx.x >> 6, lane = threadIdx.x & 63;
  int t = blockIdx.x * 4 + wid;            // source token (b, l)
  int b = (t >= LPB) ? 1 : 0;
  int l = t - b * LPB;
  int d  = l / 3136; int r = l - d * 3136;
  int hh = r / 56;   int wcol = r - hh * 56;
  int wd = d >> 1, dd = d & 1;
  int wh = hh / 7, h7 = hh - wh * 7;
  int ww = wcol / 7, w7 = wcol - ww * 7;
  int g = ((b * 8 + wd) * 8 + wh) * 8 + ww;
  int n = dd * 49 + h7 * 7 + w7;

  const float4* xp = (const float4*)(x + (size_t)t * CDIM);
  float4 v0 = xp[lane * 2], v1 = xp[lane * 2 + 1];
  float vals[8] = {v0.x, v0.y, v0.z, v0.w, v1.x, v1.y, v1.z, v1.w};
  float s = 0.f, sq = 0.f;
  #pragma unroll
  for (int j = 0; j < 8; ++j) { s += vals[j]; sq += vals[j] * vals[j]; }
  #pragma unroll
  for (int off = 32; off; off >>= 1) { s += __shfl_xor(s, off); sq += __shfl_xor(sq, off); }
  float mu = s * (1.f / 512.f);
  float var = sq * (1.f / 512.f) - mu * mu;
  float rstd = rsqrtf(var + 1e-5f);
  int c0 = lane * 8;
  float o[8];
  #pragma unroll
  for (int j = 0; j < 8; ++j) o[j] = (vals[j] - mu) * rstd * g1[c0 + j] + b1[c0 + j];
  *(uint4*)(h + (size_t)(g * NTW + n) * CDIM + c0) = pack8(o);
}

// ---------------- K5a: LN2 (identity layout), bf16 -> bf16 ----------------
__global__ __launch_bounds__(256) void ln2_kernel(const unsigned short* __restrict__ xr,
    const float* __restrict__ g2, const float* __restrict__ b2,
    unsigned short* __restrict__ t2) {
  int wid = threadIdx.x >> 6, lane = threadIdx.x & 63;
  size_t t = (size_t)blockIdx.x * 4 + wid;
  uint4 u = *((const uint4*)(xr + t * CDIM) + lane);
  float vals[8]; unpack8(u, vals);
  float s = 0.f, sq = 0.f;
  #pragma unroll
  for (int j = 0; j < 8; ++j) { s += vals[j]; sq += vals[j] * vals[j]; }
  #pragma unroll
  for (int off = 32; off; off >>= 1) { s += __shfl_xor(s, off); sq += __shfl_xor(sq, off); }
  float mu = s * (1.f / 512.f);
  float var = sq * (1.f / 512.f) - mu * mu;
  float rstd = rsqrtf(var + 1e-5f);
  int c0 = lane * 8;
  float o[8];
  #pragma unroll
  for (int j = 0; j < 8; ++j) o[j] = (vals[j] - mu) * rstd * g2[c0 + j] + b2[c0 + j];
  *(uint4*)(t2 + t * CDIM + c0) = pack8(o);
}

// ---------------- K3: window attention, MFMA 16x16x32, swapped-operand QK^T ----------------
__global__ __launch_bounds__(256, 3) void attn_kernel(const unsigned short* __restrict__ qkv,
                                                      unsigned short* __restrict__ o) {
  __shared__ unsigned short Vl[4][128 * 34];   // 8704 B per wave
  __shared__ unsigned short Pl[4][16 * 136];   // 4352 B per wave
  int tid = threadIdx.x, wid = tid >> 6, lane = tid & 63;
  int wvid = blockIdx.x * 4 + wid;
  int gw = wvid >> 4, head = wvid & 15;
  unsigned short* vl = Vl[wid];
  unsigned short* pl = Pl[wid];
  int q16 = lane & 15, hi = lane >> 4;
  const unsigned short* base = qkv + (size_t)gw * NTW * QKVLD + head * 32;

  // zero P pad cols 112..127 (rows 0..15), once
  {
    int row = lane >> 2, c0 = 112 + (lane & 3) * 4;
    uint2 z; z.x = 0; z.y = 0;
    *(uint2*)&pl[row * 136 + c0] = z;
  }
  // stage V rows 0..127 (>=98 zeroed so P_pad * V_pad == 0, never NaN)
  {
    int tb = lane >> 2, d0 = (lane & 3) * 8;
    for (int i = 0; i < 8; ++i) {
      int tok = i * 16 + tb;
      uint4 g; g.x = 0; g.y = 0; g.z = 0; g.w = 0;
      if (tok < NTW) g = *(const uint4*)(base + (size_t)tok * QKVLD + 1024 + d0);
      unsigned short* w = vl + tok * 34 + d0;
      *(unsigned*)(w)     = g.x; *(unsigned*)(w + 2) = g.y;
      *(unsigned*)(w + 4) = g.z; *(unsigned*)(w + 6) = g.w;
    }
  }
  // K fragments direct from global: lane holds K[t*16+q16][hi*8+j]
  bf16x8 kf[7];
  #pragma unroll
  for (int t = 0; t < 7; ++t) {
    uint4 u = *(const uint4*)(base + (size_t)(t * 16 + q16) * QKVLD + 512 + hi * 8);
    kf[t] = __builtin_bit_cast(bf16x8, u);
  }
  // V B-fragments from LDS: lane holds V[kk*32+hi*8+j][dt*16+q16]; reused across all M-tiles
  bf16x8 vf[4][2];
  #pragma unroll
  for (int kk = 0; kk < 4; ++kk)
    #pragma unroll
    for (int dt = 0; dt < 2; ++dt) {
      bf16x8 f;
      #pragma unroll
      for (int j = 0; j < 8; ++j)
        f[j] = ((const __bf16*)vl)[(kk * 32 + hi * 8 + j) * 34 + dt * 16 + q16];
      vf[kk][dt] = f;
    }

  for (int mt = 0; mt < 7; ++mt) {
    uint4 qu = *(const uint4*)(base + (size_t)(mt * 16 + q16) * QKVLD + hi * 8);
    bf16x8 qf = __builtin_bit_cast(bf16x8, qu);
    f32x4 s[7];
    #pragma unroll
    for (int kt = 0; kt < 7; ++kt) {
      f32x4 z = {0.f, 0.f, 0.f, 0.f};
      s[kt] = __builtin_amdgcn_mfma_f32_16x16x32_bf16(kf[kt], qf, z, 0, 0, 0);
    }
    // lane-local row softmax over 28 values (+2 shuffles for the 4 hi-groups)
    float sc[28]; float mx = -3.0e38f;
    #pragma unroll
    for (int kt = 0; kt < 7; ++kt)
      #pragma unroll
      for (int r = 0; r < 4; ++r) {
        int ktok = kt * 16 + hi * 4 + r;
        float v = (ktok < NTW) ? s[kt][r] * 0.17677669529663687f : -3.0e38f;
        sc[kt * 4 + r] = v; mx = fmaxf(mx, v);
      }
    mx = fmaxf(mx, __shfl_xor(mx, 16));
    mx = fmaxf(mx, __shfl_xor(mx, 32));
    float sum = 0.f;
    #pragma unroll
    for (int i = 0; i < 28; ++i) { sc[i] = __expf(sc[i] - mx); sum += sc[i]; }
    sum += __shfl_xor(sum, 16);
    sum += __shfl_xor(sum, 32);
    float inv = 1.f / sum;
    // write normalized P (bf16) to LDS
    #pragma unroll
    for (int kt = 0; kt < 7; ++kt) {
      unsigned p0 = (unsigned)f2bf(sc[kt * 4 + 0] * inv) | ((unsigned)f2bf(sc[kt * 4 + 1] * inv) << 16);
      unsigned p1 = (unsigned)f2bf(sc[kt * 4 + 2] * inv) | ((unsigned)f2bf(sc[kt * 4 + 3] * inv) << 16);
      uint2 w; w.x = p0; w.y = p1;
      *(uint2*)&pl[q16 * 136 + kt * 16 + hi * 4] = w;
    }
    // PV: O[16x32] = P[16x128] * V[128x32]
    f32x4 oacc0 = {0.f, 0.f, 0.f, 0.f}, oacc1 = {0.f, 0.f, 0.f, 0.f};
    #pragma unroll
    for (int kk = 0; kk < 4; ++kk) {
      uint4 pu = *(const uint4*)&pl[q16 * 136 + kk * 32 + hi * 8];
      bf16x8 pf = __builtin_bit_cast(bf16x8, pu);
      oacc0 = __builtin_amdgcn_mfma_f32_16x16x32_bf16(pf, vf[kk][0], oacc0, 0, 0, 0);
      oacc1 = __builtin_amdgcn_mfma_f32_16x16x32_bf16(pf, vf[kk][1], oacc1, 0, 0, 0);
    }
    // store: lane holds O[q=hi*4+r][dim=q16] per dim-tile
    #pragma unroll
    for (int r = 0; r < 4; ++r) {
      int tok = mt * 16 + hi * 4 + r;
      if (tok < NTW) {
        unsigned short* op = o + (size_t)(gw * NTW + tok) * CDIM + head * 32 + q16;
        op[0]  = f2bf(oacc0[r]);
        op[16] = f2bf(oacc1[r]);
      }
    }
  }
}

// ======================= GEMM A: 256x256 tile, 8-wave, 8-phase (round-9 schedule) =======================
// TRANSPOSED ACCUMULATION: acc = mfma(b_frag, a_frag) -> lane&15 = M-row, hi*4+rr = N-col.
// Epilogue: 4 consecutive cols in-lane -> cvt_pk pairs + one 8B/16B store per (mi,ni).
enum { EPI_BF16 = 0, EPI_PERM = 1, EPI_GELU = 2, EPI_RES = 3 };

#define GL2A(as_, kofs, half) do { \
  const unsigned short* ga_ = gA + (kofs) + (size_t)((half) * 128) * K; \
  gl2lds16(ga_,                  (as_) + (half) * 8192 + wid * 512); \
  gl2lds16(ga_ + (size_t)64 * K, (as_) + (half) * 8192 + 4096 + wid * 512); \
} while (0)
#define GL2B(bs_, kofs, half) do { \
  const unsigned short* gb_ = gB + (kofs) + (size_t)((half) * 128) * K; \
  gl2lds16(gb_,                  (bs_) + (half) * 8192 + wid * 512); \
  gl2lds16(gb_ + (size_t)64 * K, (bs_) + (half) * 8192 + 4096 + wid * 512); \
} while (0)

#define RD16(buf, row, cb) __builtin_bit_cast(bf16x8, *(const uint4*)((buf) + (row) * 64 + ((cb) >> 1)))
#define READ_A4(dst, buf, mofs) { _Pragma("unroll") for (int m_ = 0; m_ < 4; ++m_) { \
    dst[m_][0] = RD16(buf, arow + (mofs) + m_ * 16, cb0); \
    dst[m_][1] = RD16(buf, arow + (mofs) + m_ * 16, cb1); } }
#define READ_B2(dst, buf, nofs) { _Pragma("unroll") for (int n_ = 0; n_ < 2; ++n_) { \
    dst[n_][0] = RD16(buf, brow + (nofs) + n_ * 16, cb0); \
    dst[n_][1] = RD16(buf, brow + (nofs) + n_ * 16, cb1); } }
#define MFMA_Q8(mh, nh, av, bv) { _Pragma("unroll") for (int m_ = 0; m_ < 4; ++m_) \
  _Pragma("unroll") for (int n_ = 0; n_ < 2; ++n_) { \
    acc[(mh)*4+m_][(nh)*2+n_] = __builtin_amdgcn_mfma_f32_16x16x32_bf16(bv[n_][0], av[m_][0], acc[(mh)*4+m_][(nh)*2+n_], 0, 0, 0); \
    acc[(mh)*4+m_][(nh)*2+n_] = __builtin_amdgcn_mfma_f32_16x16x32_bf16(bv[n_][1], av[m_][1], acc[(mh)*4+m_][(nh)*2+n_], 0, 0, 0); } }
#define PHASE_MFMA8(mh, nh, av, bv) \
  __builtin_amdgcn_s_barrier(); \
  asm volatile("s_waitcnt lgkmcnt(0)" ::: "memory"); \
  __builtin_amdgcn_sched_barrier(0); \
  __builtin_amdgcn_s_setprio(1); \
  MFMA_Q8(mh, nh, av, bv); \
  __builtin_amdgcn_s_setprio(0);
#define ENDBAR() { __builtin_amdgcn_sched_barrier(0); __builtin_amdgcn_s_barrier(); }

// shared epilogue body: lane holds one row (r16) x 4 consecutive cols (hi*4+rr)
#define EPILOG_TILE(acc_v) { \
  int colb = c0 + ni * 16 + (hi << 2); \
  float4 bs4 = *(const float4*)&bias[colb]; \
  float v0 = acc_v[0] + bs4.x, v1 = acc_v[1] + bs4.y; \
  float v2 = acc_v[2] + bs4.z, v3 = acc_v[3] + bs4.w; \
  if (EPI == EPI_GELU) { v0 = gelu_f(v0); v1 = gelu_f(v1); v2 = gelu_f(v2); v3 = gelu_f(v3); } \
  if (EPI == EPI_RES) { \
    uint2 ru = *(const uint2*)(resid + rowoff + colb); \
    float4 o4; \
    o4.x = v0 + bf2f((unsigned short)(ru.x & 0xffff)); \
    o4.y = v1 + bf2f((unsigned short)(ru.x >> 16)); \
    o4.z = v2 + bf2f((unsigned short)(ru.y & 0xffff)); \
    o4.w = v3 + bf2f((unsigned short)(ru.y >> 16)); \
    *(float4*)(outf + rowoff + colb) = o4; \
  } else { \
    uint2 w; w.x = cvtpk(v0, v1); w.y = cvtpk(v2, v3); \
    *(uint2*)(outb + rowoff + colb) = w; \
  } }

#define PERM_ROWOFF() { \
  int gwin = rowg / NTW; int nn = rowg - gwin * NTW; \
  int b = gwin >> 9, wd = (gwin >> 6) & 7, wh = (gwin >> 3) & 7, ww = gwin & 7; \
  int dd = nn / 49; int rr2 = nn - dd * 49; int hh = rr2 / 7; int w7 = rr2 - hh * 7; \
  int lflat = (wd * 2 + dd) * 3136 + (wh * 7 + hh) * 56 + (ww * 7 + w7); \
  rowoff = (size_t)(b * LPB + lflat) * N; }

template<int EPI>
__global__ __launch_bounds__(512, 2) void gemm256_kernel(
    const unsigned short* __restrict__ A,
    const unsigned short* __restrict__ Bt,
    const float* __restrict__ bias,
    unsigned short* __restrict__ outb,
    float* __restrict__ outf,
    const unsigned short* __restrict__ resid,
    int M, int N, int K) {
  extern __shared__ __attribute__((aligned(16))) unsigned short lds[];
  unsigned short* AS0 = lds;
  unsigned short* AS1 = lds + 16384;
  unsigned short* BS0 = lds + 32768;
  unsigned short* BS1 = lds + 49152;
  int tid = threadIdx.x, lane = tid & 63, wid = tid >> 6;
  int wm = wid >> 2, wn = wid & 3;
  int nwg = gridDim.x;
  int id = (int)(blockIdx.x & 7) * (nwg >> 3) + (int)(blockIdx.x >> 3);
  int nC = N >> 8;
  int rowBase = (id / nC) << 8, colBase = (id % nC) << 8;

  int srow = lane >> 3;
  int scol = ((lane & 7) ^ srow) << 3;
  const unsigned short* gA = A  + (size_t)(rowBase + wid * 8 + srow) * K + scol;
  const unsigned short* gB = Bt + (size_t)(colBase + wid * 8 + srow) * K + scol;

  int r16 = lane & 15, hi = lane >> 4;
  int cxor = (lane & 7) << 4;
  int cb0 = (hi << 4) ^ cxor;
  int cb1 = (64 + (hi << 4)) ^ cxor;
  int arow = wm * 128 + r16;
  int brow = wn * 64 + r16;

  f32x4 acc[8][4] = {};
  bf16x8 a0[4][2], a1[4][2], b0[2][2], b1[2][2];

  int T = K >> 6, halfT = T >> 1;

  GL2A(AS0, 0, 0); GL2A(AS0, 0, 1);
  GL2B(BS0, 0, 0); GL2B(BS0, 0, 1);
  GL2A(AS1, 64, 0);
  asm volatile("s_waitcnt vmcnt(2)" ::: "memory");
  __builtin_amdgcn_s_barrier();

  for (int i = 0; i < halfT; ++i) {
    int e = 2 * i;
    int kE1 = (e + 1) << 6, kE2 = (e + 2) << 6, kE3 = (e + 3) << 6;
    bool s2 = (e + 2 < T), s3 = (e + 3 < T);
    READ_A4(a0, AS0, 0); READ_B2(b0, BS0, 0);
    GL2A(AS1, kE1, 1);
    PHASE_MFMA8(0, 0, a0, b0); ENDBAR();
    READ_B2(b1, BS0, 32);
    GL2B(BS1, kE1, 0);
    PHASE_MFMA8(0, 1, a0, b1); ENDBAR();
    READ_A4(a1, AS0, 64);
    GL2B(BS1, kE1, 1);
    PHASE_MFMA8(1, 0, a1, b0); ENDBAR();
    if (s2) GL2A(AS0, kE2, 0);
    PHASE_MFMA8(1, 1, a1, b1);
    if (s2) { asm volatile("s_waitcnt vmcnt(2)" ::: "memory"); }
    else    { asm volatile("s_waitcnt vmcnt(0)" ::: "memory"); }
    ENDBAR();
    READ_A4(a0, AS1, 0); READ_B2(b0, BS1, 0);
    if (s2) GL2A(AS0, kE2, 1);
    PHASE_MFMA8(0, 0, a0, b0); ENDBAR();
    READ_B2(b1, BS1, 32);
    if (s2) GL2B(BS0, kE2, 0);
    PHASE_MFMA8(0, 1, a0, b1); ENDBAR();
    READ_A4(a1, AS1, 64);
    if (s2) GL2B(BS0, kE2, 1);
    PHASE_MFMA8(1, 0, a1, b0); ENDBAR();
    if (s3) GL2A(AS1, kE3, 0);
    PHASE_MFMA8(1, 1, a1, b1);
    if (s3) { asm volatile("s_waitcnt vmcnt(2)" ::: "memory"); }
    else    { asm volatile("s_waitcnt vmcnt(0)" ::: "memory"); }
    ENDBAR();
  }

  int r0 = rowBase + wm * 128, c0 = colBase + wn * 64;
  #pragma unroll
  for (int mi = 0; mi < 8; ++mi) {
    int rowg = r0 + mi * 16 + r16;
    size_t rowoff;
    if (EPI == EPI_PERM) { PERM_ROWOFF(); } else { rowoff = (size_t)rowg * N; }
    #pragma unroll
    for (int ni = 0; ni < 4; ++ni) {
      EPILOG_TILE(acc[mi][ni]);
    }
  }
}

// ======================= GEMM B: 128x128 tile, 4-wave, 8-phase (round-16 schedule) =======================
#define GL2A4(as_, kofs, half) do { \
  const unsigned short* ga_ = gA + (kofs) + (size_t)((half) * 64) * K; \
  gl2lds16(ga_,                  (as_) + (half) * 4096 + wid * 512); \
  gl2lds16(ga_ + (size_t)32 * K, (as_) + (half) * 4096 + 2048 + wid * 512); \
} while (0)
#define GL2B4(bs_, kofs, half) do { \
  const unsigned short* gb_ = gB + (kofs) + (size_t)((half) * 64) * K; \
  gl2lds16(gb_,                  (bs_) + (half) * 4096 + wid * 512); \
  gl2lds16(gb_ + (size_t)32 * K, (bs_) + (half) * 4096 + 2048 + wid * 512); \
} while (0)
#define READ_A2(dst, buf, mofs) { _Pragma("unroll") for (int m_ = 0; m_ < 2; ++m_) { \
    dst[m_][0] = RD16(buf, arow + (mofs) + m_ * 16, cb0); \
    dst[m_][1] = RD16(buf, arow + (mofs) + m_ * 16, cb1); } }
#define MFMA_Q4(mh, nh, av, bv) { _Pragma("unroll") for (int m_ = 0; m_ < 2; ++m_) \
  _Pragma("unroll") for (int n_ = 0; n_ < 2; ++n_) { \
    acc[(mh)*2+m_][(nh)*2+n_] = __builtin_amdgcn_mfma_f32_16x16x32_bf16(bv[n_][0], av[m_][0], acc[(mh)*2+m_][(nh)*2+n_], 0, 0, 0); \
    acc[(mh)*2+m_][(nh)*2+n_] = __builtin_amdgcn_mfma_f32_16x16x32_bf16(bv[n_][1], av[m_][1], acc[(mh)*2+m_][(nh)*2+n_], 0, 0, 0); } }
#define PHASE_MFMA4(mh, nh, av, bv) \
  __builtin_amdgcn_s_barrier(); \
  asm volatile("s_waitcnt lgkmcnt(0)" ::: "memory"); \
  __builtin_amdgcn_sched_barrier(0); \
  __builtin_amdgcn_s_setprio(1); \
  MFMA_Q4(mh, nh, av, bv); \
  __builtin_amdgcn_s_setprio(0);

template<int EPI>
__global__ __launch_bounds__(256, 2) void gemm128_kernel(
    const unsigned short* __restrict__ A,
    const unsigned short* __restrict__ Bt,
    const float* __restrict__ bias,
    unsigned short* __restrict__ outb,
    float* __restrict__ outf,
    const unsigned short* __restrict__ resid,
    int M, int N, int K) {
  extern __shared__ __attribute__((aligned(16))) unsigned short lds[];
  unsigned short* AS0 = lds;
  unsigned short* AS1 = lds + 8192;
  unsigned short* BS0 = lds + 16384;
  unsigned short* BS1 = lds + 24576;
  int tid = threadIdx.x, lane = tid & 63, wid = tid >> 6;
  int wm = wid >> 1, wn = wid & 1;
  int nwg = gridDim.x;
  int id = (int)(blockIdx.x & 7) * (nwg >> 3) + (int)(blockIdx.x >> 3);
  int nC = N >> 7;
  int rowBase = (id / nC) << 7, colBase = (id % nC) << 7;

  int srow = lane >> 3;
  int scol = ((lane & 7) ^ srow) << 3;
  const unsigned short* gA = A  + (size_t)(rowBase + wid * 8 + srow) * K + scol;
  const unsigned short* gB = Bt + (size_t)(colBase + wid * 8 + srow) * K + scol;

  int r16 = lane & 15, hi = lane >> 4;
  int cxor = (lane & 7) << 4;
  int cb0 = (hi << 4) ^ cxor;
  int cb1 = (64 + (hi << 4)) ^ cxor;
  int arow = wm * 64 + r16;
  int brow = wn * 64 + r16;

  f32x4 acc[4][4] = {};
  bf16x8 a0[2][2], a1[2][2], b0[2][2], b1[2][2];

  int T = K >> 6, halfT = T >> 1;

  GL2A4(AS0, 0, 0); GL2A4(AS0, 0, 1);
  GL2B4(BS0, 0, 0); GL2B4(BS0, 0, 1);
  GL2A4(AS1, 64, 0);
  asm volatile("s_waitcnt vmcnt(2)" ::: "memory");
  __builtin_amdgcn_s_barrier();

  for (int i = 0; i < halfT; ++i) {
    int e = 2 * i;
    int kE1 = (e + 1) << 6, kE2 = (e + 2) << 6, kE3 = (e + 3) << 6;
    bool s2 = (e + 2 < T), s3 = (e + 3 < T);
    READ_A2(a0, AS0, 0); READ_B2(b0, BS0, 0);
    GL2A4(AS1, kE1, 1);
    PHASE_MFMA4(0, 0, a0, b0); ENDBAR();
    READ_B2(b1, BS0, 32);
    GL2B4(BS1, kE1, 0);
    PHASE_MFMA4(0, 1, a0, b1); ENDBAR();
    READ_A2(a1, AS0, 32);
    GL2B4(BS1, kE1, 1);
    PHASE_MFMA4(1, 0, a1, b0); ENDBAR();
    if (s2) GL2A4(AS0, kE2, 0);
    PHASE_MFMA4(1, 1, a1, b1);
    if (s2) { asm volatile("s_waitcnt vmcnt(2)" ::: "memory"); }
    else    { asm volatile("s_waitcnt vmcnt(0)" ::: "memory"); }
    ENDBAR();
    READ_A2(a0, AS1, 0); READ_B2(b0, BS1, 0);
    if (s2) GL2A4(AS0, kE2, 1);
    PHASE_MFMA4(0, 0, a0, b0); ENDBAR();
    READ_B2(b1, BS1, 32);
    if (s2) GL2B4(BS0, kE2, 0);
    PHASE_MFMA4(0, 1, a0, b1); ENDBAR();
    READ_A2(a1, AS1, 32);
    if (s2) GL2B4(BS0, kE2, 1);
    PHASE_MFMA4(1, 0, a1, b0); ENDBAR();
    if (s3) GL2A4(AS1, kE3, 0);
    PHASE_MFMA4(1, 1, a1, b1);
    if (s3) { asm volatile("s_waitcnt vmcnt(2)" ::: "memory"); }
    else    { asm volatile("s_waitcnt vmcnt(0)" ::: "memory"); }
    ENDBAR();
  }

  int r0 = rowBase + wm * 64, c0 = colBase + wn * 64;
  #pragma unroll
  for (int mi = 0; mi < 4; ++mi) {
    int rowg = r0 + mi * 16 + r16;
    size_t rowoff;
    if (EPI == EPI_PERM) { PERM_ROWOFF(); } else { rowoff = (size_t)rowg * N; }
    #pragma unroll
    for (int ni = 0; ni < 4; ++ni) {
      EPILOG_TILE(acc[mi][ni]);
    }
  }
}

extern "C" void kernel_launch(void* const* d_in, const int* in_sizes, int n_in,
                              void* d_out, int out_size, void* d_ws, size_t ws_size,
                              hipStream_t stream) {
  const float* x     = (const float*)d_in[0];
  const float* g1    = (const float*)d_in[1];
  const float* b1    = (const float*)d_in[2];
  const float* wqkv  = (const float*)d_in[3];
  const float* bqkv  = (const float*)d_in[4];
  const float* wproj = (const float*)d_in[5];
  const float* bproj = (const float*)d_in[6];
  const float* g2    = (const float*)d_in[7];
  const float* b2    = (const float*)d_in[8];
  const float* w1    = (const float*)d_in[9];
  const float* bm1   = (const float*)d_in[10];
  const float* w2    = (const float*)d_in[11];
  const float* bm2   = (const float*)d_in[12];
  float* y = (float*)d_out;
  char* ws = (char*)d_ws;

  // workspace layout (bytes)
  unsigned short* wqkvT  = (unsigned short*)(ws + 0);          // 1536x512   -> 1,572,864
  unsigned short* wprojT = (unsigned short*)(ws + 1572864);    // 512x512    ->   524,288
  unsigned short* w1T    = (unsigned short*)(ws + 2097152);    // 2048x512   -> 2,097,152
  unsigned short* w2T    = (unsigned short*)(ws + 4194304);    // 512x2048   -> 2,097,152
  const size_t OFF = (size_t)8 << 20;
  const size_t ACT = (size_t)NTOK * CDIM * 2;                  // 102,760,448
  unsigned short* bufB = (unsigned short*)(ws + OFF);          // h / o / t2
  unsigned short* xr   = (unsigned short*)(ws + OFF + ACT);    // xr (bf16)
  unsigned short* bufA = (unsigned short*)(ws + OFF + 2 * ACT);// qkv / mid (max 411,041,792)
  const size_t NEEDED = OFF + 2 * ACT + (size_t)NTOK * MLPDIM * 2;
  if (ws_size < NEEDED) return;  // diagnosable: zero output, ~0 time

  const int SMEM256 = 131072;  // 128 KiB for the 256^2 GEMM
  const int SMEM128 = 65536;   // 64 KiB for the 128^2 GEMM
  (void)hipFuncSetAttribute((const void*)&gemm256_kernel<EPI_BF16>, hipFuncAttributeMaxDynamicSharedMemorySize, SMEM256);
  (void)hipFuncSetAttribute((const void*)&gemm256_kernel<EPI_PERM>, hipFuncAttributeMaxDynamicSharedMemorySize, SMEM256);
  (void)hipFuncSetAttribute((const void*)&gemm256_kernel<EPI_RES>,  hipFuncAttributeMaxDynamicSharedMemorySize, SMEM256);
  (void)hipFuncSetAttribute((const void*)&gemm128_kernel<EPI_GELU>, hipFuncAttributeMaxDynamicSharedMemorySize, SMEM128);

  // K0: weights -> bf16 transposed
  cvt_t_kernel<<<(1536 * 512 + 255) / 256, 256, 0, stream>>>(wqkv, wqkvT, 9, 1536, 1536 * 512);
  cvt_t_kernel<<<(512 * 512 + 255) / 256, 256, 0, stream>>>(wproj, wprojT, 9, 512, 512 * 512);
  cvt_t_kernel<<<(2048 * 512 + 255) / 256, 256, 0, stream>>>(w1, w1T, 9, 2048, 2048 * 512);
  cvt_t_kernel<<<(512 * 2048 + 255) / 256, 256, 0, stream>>>(w2, w2T, 11, 512, 512 * 2048);
  // K1: LN1 + partition -> h (bufB)
  ln1_kernel<<<NTOK / 4, 256, 0, stream>>>(x, g1, b1, bufB);
  // K2: QKV GEMM -> qkv (bufA)   [256^2]
  gemm256_kernel<EPI_BF16><<<(NTOK / 256) * (1536 / 256), 512, SMEM256, stream>>>(
      bufB, wqkvT, bqkv, bufA, nullptr, nullptr, NTOK, 1536, 512);
  // K3: attention -> o (bufB, h is dead)
  attn_kernel<<<(1024 * 16) / 4, 256, 0, stream>>>(bufA, bufB);
  // K4: proj GEMM + window reverse -> xr   [256^2]
  gemm256_kernel<EPI_PERM><<<(NTOK / 256) * (512 / 256), 512, SMEM256, stream>>>(
      bufB, wprojT, bproj, xr, nullptr, nullptr, NTOK, 512, 512);
  // K5a: LN2 -> t2 (bufB, o is dead)
  ln2_kernel<<<NTOK / 4, 256, 0, stream>>>(xr, g2, b2, bufB);
  // K5b: MLP1 + gelu -> mid (bufA, qkv is dead)   [128^2]
  gemm128_kernel<EPI_GELU><<<(NTOK / 128) * (2048 / 128), 256, SMEM128, stream>>>(
      bufB, w1T, bm1, bufA, nullptr, nullptr, NTOK, 2048, 512);
  // K6: MLP2 + bias + residual -> y (fp32)   [256^2]
  gemm256_kernel<EPI_RES><<<(NTOK / 256) * (512 / 256), 512, SMEM256, stream>>>(
      bufA, w2T, bm2, nullptr, y, xr, NTOK, 512, 2048);
}

// Round 19
// 1172.861 us; speedup vs baseline: 1.0685x; 1.0685x over previous
//
#include <hip/hip_runtime.h>
#include <hip/hip_bf16.h>
#include <cstdint>

#define CDIM 512
#define NTOK 100352   // 2 * 16*56*56
#define LPB  50176    // tokens per batch
#define NTW  98       // tokens per window
#define QKVLD 1536
#define MLPDIM 2048

typedef __bf16 bf16x8 __attribute__((ext_vector_type(8)));
typedef float  f32x4  __attribute__((ext_vector_type(4)));

__device__ __forceinline__ float bf2f(unsigned short u) {
  union { unsigned int i; float f; } v; v.i = ((unsigned int)u) << 16; return v.f;
}
__device__ __forceinline__ unsigned short f2bf(float f) {
  union { float f; unsigned int i; } v; v.f = f;
  unsigned int u = v.i;
  return (unsigned short)((u + 0x7fffu + ((u >> 16) & 1u)) >> 16);
}
__device__ __forceinline__ void unpack8(uint4 u, float* f) {
  f[0] = bf2f((unsigned short)(u.x & 0xffff)); f[1] = bf2f((unsigned short)(u.x >> 16));
  f[2] = bf2f((unsigned short)(u.y & 0xffff)); f[3] = bf2f((unsigned short)(u.y >> 16));
  f[4] = bf2f((unsigned short)(u.z & 0xffff)); f[5] = bf2f((unsigned short)(u.z >> 16));
  f[6] = bf2f((unsigned short)(u.w & 0xffff)); f[7] = bf2f((unsigned short)(u.w >> 16));
}
__device__ __forceinline__ uint4 pack8(const float* f) {
  uint4 u;
  u.x = (unsigned)f2bf(f[0]) | ((unsigned)f2bf(f[1]) << 16);
  u.y = (unsigned)f2bf(f[2]) | ((unsigned)f2bf(f[3]) << 16);
  u.z = (unsigned)f2bf(f[4]) | ((unsigned)f2bf(f[5]) << 16);
  u.w = (unsigned)f2bf(f[6]) | ((unsigned)f2bf(f[7]) << 16);
  return u;
}
__device__ __forceinline__ float gelu_f(float v) {
  float u = 0.7978845608028654f * (v + 0.044715f * v * v * v);
  float e = __expf(2.f * u);
  float t = 1.f - 2.f / (1.f + e);
  return 0.5f * v * (1.f + t);
}
__device__ __forceinline__ void gl2lds16(const unsigned short* g, unsigned short* l) {
  __builtin_amdgcn_global_load_lds((const __attribute__((address_space(1))) void*)g,
                                   (__attribute__((address_space(3))) void*)l, 16, 0, 0);
}

// ---------------- K0: weight fp32 KxN -> bf16 NxK (transpose + convert) ----------------
__global__ void cvt_t_kernel(const float* __restrict__ src, unsigned short* __restrict__ dst,
                             int lk, int N, int total) {
  int idx = blockIdx.x * 256 + threadIdx.x;
  if (idx >= total) return;
  int K = 1 << lk;
  int nn = idx >> lk, kk = idx & (K - 1);
  dst[idx] = f2bf(src[kk * N + nn]);
}

// ---------------- K1: LN1 + window partition, fp32 -> bf16 ----------------
__global__ __launch_bounds__(256) void ln1_kernel(const float* __restrict__ x,
    const float* __restrict__ g1, const float* __restrict__ b1,
    unsigned short* __restrict__ h) {
  int wid = threadIdx.x >> 6, lane = threadIdx.x & 63;
  int t = blockIdx.x * 4 + wid;            // source token (b, l)
  int b = (t >= LPB) ? 1 : 0;
  int l = t - b * LPB;
  int d  = l / 3136; int r = l - d * 3136;
  int hh = r / 56;   int wcol = r - hh * 56;
  int wd = d >> 1, dd = d & 1;
  int wh = hh / 7, h7 = hh - wh * 7;
  int ww = wcol / 7, w7 = wcol - ww * 7;
  int g = ((b * 8 + wd) * 8 + wh) * 8 + ww;
  int n = dd * 49 + h7 * 7 + w7;

  const float4* xp = (const float4*)(x + (size_t)t * CDIM);
  float4 v0 = xp[lane * 2], v1 = xp[lane * 2 + 1];
  float vals[8] = {v0.x, v0.y, v0.z, v0.w, v1.x, v1.y, v1.z, v1.w};
  float s = 0.f, sq = 0.f;
  #pragma unroll
  for (int j = 0; j < 8; ++j) { s += vals[j]; sq += vals[j] * vals[j]; }
  #pragma unroll
  for (int off = 32; off; off >>= 1) { s += __shfl_xor(s, off); sq += __shfl_xor(sq, off); }
  float mu = s * (1.f / 512.f);
  float var = sq * (1.f / 512.f) - mu * mu;
  float rstd = rsqrtf(var + 1e-5f);
  int c0 = lane * 8;
  float o[8];
  #pragma unroll
  for (int j = 0; j < 8; ++j) o[j] = (vals[j] - mu) * rstd * g1[c0 + j] + b1[c0 + j];
  *(uint4*)(h + (size_t)(g * NTW + n) * CDIM + c0) = pack8(o);
}

// ---------------- K5a: LN2 (identity layout), bf16 -> bf16 ----------------
__global__ __launch_bounds__(256) void ln2_kernel(const unsigned short* __restrict__ xr,
    const float* __restrict__ g2, const float* __restrict__ b2,
    unsigned short* __restrict__ t2) {
  int wid = threadIdx.x >> 6, lane = threadIdx.x & 63;
  size_t t = (size_t)blockIdx.x * 4 + wid;
  uint4 u = *((const uint4*)(xr + t * CDIM) + lane);
  float vals[8]; unpack8(u, vals);
  float s = 0.f, sq = 0.f;
  #pragma unroll
  for (int j = 0; j < 8; ++j) { s += vals[j]; sq += vals[j] * vals[j]; }
  #pragma unroll
  for (int off = 32; off; off >>= 1) { s += __shfl_xor(s, off); sq += __shfl_xor(sq, off); }
  float mu = s * (1.f / 512.f);
  float var = sq * (1.f / 512.f) - mu * mu;
  float rstd = rsqrtf(var + 1e-5f);
  int c0 = lane * 8;
  float o[8];
  #pragma unroll
  for (int j = 0; j < 8; ++j) o[j] = (vals[j] - mu) * rstd * g2[c0 + j] + b2[c0 + j];
  *(uint4*)(t2 + t * CDIM + c0) = pack8(o);
}

// ---------------- K3: window attention, MFMA 16x16x32, swapped-operand QK^T ----------------
__global__ __launch_bounds__(256, 3) void attn_kernel(const unsigned short* __restrict__ qkv,
                                                      unsigned short* __restrict__ o) {
  __shared__ unsigned short Vl[4][128 * 34];   // 8704 B per wave
  __shared__ unsigned short Pl[4][16 * 136];   // 4352 B per wave
  int tid = threadIdx.x, wid = tid >> 6, lane = tid & 63;
  int wvid = blockIdx.x * 4 + wid;
  int gw = wvid >> 4, head = wvid & 15;
  unsigned short* vl = Vl[wid];
  unsigned short* pl = Pl[wid];
  int q16 = lane & 15, hi = lane >> 4;
  const unsigned short* base = qkv + (size_t)gw * NTW * QKVLD + head * 32;

  // zero P pad cols 112..127 (rows 0..15), once
  {
    int row = lane >> 2, c0 = 112 + (lane & 3) * 4;
    uint2 z; z.x = 0; z.y = 0;
    *(uint2*)&pl[row * 136 + c0] = z;
  }
  // stage V rows 0..127 (>=98 zeroed so P_pad * V_pad == 0, never NaN)
  {
    int tb = lane >> 2, d0 = (lane & 3) * 8;
    for (int i = 0; i < 8; ++i) {
      int tok = i * 16 + tb;
      uint4 g; g.x = 0; g.y = 0; g.z = 0; g.w = 0;
      if (tok < NTW) g = *(const uint4*)(base + (size_t)tok * QKVLD + 1024 + d0);
      unsigned short* w = vl + tok * 34 + d0;
      *(unsigned*)(w)     = g.x; *(unsigned*)(w + 2) = g.y;
      *(unsigned*)(w + 4) = g.z; *(unsigned*)(w + 6) = g.w;
    }
  }
  // K fragments direct from global: lane holds K[t*16+q16][hi*8+j]
  bf16x8 kf[7];
  #pragma unroll
  for (int t = 0; t < 7; ++t) {
    uint4 u = *(const uint4*)(base + (size_t)(t * 16 + q16) * QKVLD + 512 + hi * 8);
    kf[t] = __builtin_bit_cast(bf16x8, u);
  }
  // V B-fragments from LDS: lane holds V[kk*32+hi*8+j][dt*16+q16]; reused across all M-tiles
  bf16x8 vf[4][2];
  #pragma unroll
  for (int kk = 0; kk < 4; ++kk)
    #pragma unroll
    for (int dt = 0; dt < 2; ++dt) {
      bf16x8 f;
      #pragma unroll
      for (int j = 0; j < 8; ++j)
        f[j] = ((const __bf16*)vl)[(kk * 32 + hi * 8 + j) * 34 + dt * 16 + q16];
      vf[kk][dt] = f;
    }

  for (int mt = 0; mt < 7; ++mt) {
    uint4 qu = *(const uint4*)(base + (size_t)(mt * 16 + q16) * QKVLD + hi * 8);
    bf16x8 qf = __builtin_bit_cast(bf16x8, qu);
    f32x4 s[7];
    #pragma unroll
    for (int kt = 0; kt < 7; ++kt) {
      f32x4 z = {0.f, 0.f, 0.f, 0.f};
      s[kt] = __builtin_amdgcn_mfma_f32_16x16x32_bf16(kf[kt], qf, z, 0, 0, 0);
    }
    // lane-local row softmax over 28 values (+2 shuffles for the 4 hi-groups)
    float sc[28]; float mx = -3.0e38f;
    #pragma unroll
    for (int kt = 0; kt < 7; ++kt)
      #pragma unroll
      for (int r = 0; r < 4; ++r) {
        int ktok = kt * 16 + hi * 4 + r;
        float v = (ktok < NTW) ? s[kt][r] * 0.17677669529663687f : -3.0e38f;
        sc[kt * 4 + r] = v; mx = fmaxf(mx, v);
      }
    mx = fmaxf(mx, __shfl_xor(mx, 16));
    mx = fmaxf(mx, __shfl_xor(mx, 32));
    float sum = 0.f;
    #pragma unroll
    for (int i = 0; i < 28; ++i) { sc[i] = __expf(sc[i] - mx); sum += sc[i]; }
    sum += __shfl_xor(sum, 16);
    sum += __shfl_xor(sum, 32);
    float inv = 1.f / sum;
    // write normalized P (bf16) to LDS
    #pragma unroll
    for (int kt = 0; kt < 7; ++kt) {
      unsigned p0 = (unsigned)f2bf(sc[kt * 4 + 0] * inv) | ((unsigned)f2bf(sc[kt * 4 + 1] * inv) << 16);
      unsigned p1 = (unsigned)f2bf(sc[kt * 4 + 2] * inv) | ((unsigned)f2bf(sc[kt * 4 + 3] * inv) << 16);
      uint2 w; w.x = p0; w.y = p1;
      *(uint2*)&pl[q16 * 136 + kt * 16 + hi * 4] = w;
    }
    // PV: O[16x32] = P[16x128] * V[128x32]
    f32x4 oacc0 = {0.f, 0.f, 0.f, 0.f}, oacc1 = {0.f, 0.f, 0.f, 0.f};
    #pragma unroll
    for (int kk = 0; kk < 4; ++kk) {
      uint4 pu = *(const uint4*)&pl[q16 * 136 + kk * 32 + hi * 8];
      bf16x8 pf = __builtin_bit_cast(bf16x8, pu);
      oacc0 = __builtin_amdgcn_mfma_f32_16x16x32_bf16(pf, vf[kk][0], oacc0, 0, 0, 0);
      oacc1 = __builtin_amdgcn_mfma_f32_16x16x32_bf16(pf, vf[kk][1], oacc1, 0, 0, 0);
    }
    // store: lane holds O[q=hi*4+r][dim=q16] per dim-tile
    #pragma unroll
    for (int r = 0; r < 4; ++r) {
      int tok = mt * 16 + hi * 4 + r;
      if (tok < NTW) {
        unsigned short* op = o + (size_t)(gw * NTW + tok) * CDIM + head * 32 + q16;
        op[0]  = f2bf(oacc0[r]);
        op[16] = f2bf(oacc1[r]);
      }
    }
  }
}

// ======================= GEMM A: 256x256 tile, 8-wave, 8-phase (round-9 verified) =======================
enum { EPI_BF16 = 0, EPI_PERM = 1, EPI_GELU = 2, EPI_RES = 3 };

#define GL2A(as_, kofs, half) do { \
  const unsigned short* ga_ = gA + (kofs) + (size_t)((half) * 128) * K; \
  gl2lds16(ga_,                  (as_) + (half) * 8192 + wid * 512); \
  gl2lds16(ga_ + (size_t)64 * K, (as_) + (half) * 8192 + 4096 + wid * 512); \
} while (0)
#define GL2B(bs_, kofs, half) do { \
  const unsigned short* gb_ = gB + (kofs) + (size_t)((half) * 128) * K; \
  gl2lds16(gb_,                  (bs_) + (half) * 8192 + wid * 512); \
  gl2lds16(gb_ + (size_t)64 * K, (bs_) + (half) * 8192 + 4096 + wid * 512); \
} while (0)

#define RD16(buf, row, cb) __builtin_bit_cast(bf16x8, *(const uint4*)((buf) + (row) * 64 + ((cb) >> 1)))
#define READ_A4(dst, buf, mofs) { _Pragma("unroll") for (int m_ = 0; m_ < 4; ++m_) { \
    dst[m_][0] = RD16(buf, arow + (mofs) + m_ * 16, cb0); \
    dst[m_][1] = RD16(buf, arow + (mofs) + m_ * 16, cb1); } }
#define READ_B2(dst, buf, nofs) { _Pragma("unroll") for (int n_ = 0; n_ < 2; ++n_) { \
    dst[n_][0] = RD16(buf, brow + (nofs) + n_ * 16, cb0); \
    dst[n_][1] = RD16(buf, brow + (nofs) + n_ * 16, cb1); } }
#define MFMA_Q8(mh, nh, av, bv) { _Pragma("unroll") for (int m_ = 0; m_ < 4; ++m_) \
  _Pragma("unroll") for (int n_ = 0; n_ < 2; ++n_) { \
    acc[(mh)*4+m_][(nh)*2+n_] = __builtin_amdgcn_mfma_f32_16x16x32_bf16(av[m_][0], bv[n_][0], acc[(mh)*4+m_][(nh)*2+n_], 0, 0, 0); \
    acc[(mh)*4+m_][(nh)*2+n_] = __builtin_amdgcn_mfma_f32_16x16x32_bf16(av[m_][1], bv[n_][1], acc[(mh)*4+m_][(nh)*2+n_], 0, 0, 0); } }
#define PHASE_MFMA8(mh, nh, av, bv) \
  __builtin_amdgcn_s_barrier(); \
  asm volatile("s_waitcnt lgkmcnt(0)" ::: "memory"); \
  __builtin_amdgcn_sched_barrier(0); \
  __builtin_amdgcn_s_setprio(1); \
  MFMA_Q8(mh, nh, av, bv); \
  __builtin_amdgcn_s_setprio(0);
#define ENDBAR() { __builtin_amdgcn_sched_barrier(0); __builtin_amdgcn_s_barrier(); }

template<int EPI>
__global__ __launch_bounds__(512, 2) void gemm256_kernel(
    const unsigned short* __restrict__ A,
    const unsigned short* __restrict__ Bt,
    const float* __restrict__ bias,
    unsigned short* __restrict__ outb,
    float* __restrict__ outf,
    const unsigned short* __restrict__ resid,
    int M, int N, int K) {
  extern __shared__ __attribute__((aligned(16))) unsigned short lds[];
  unsigned short* AS0 = lds;
  unsigned short* AS1 = lds + 16384;
  unsigned short* BS0 = lds + 32768;
  unsigned short* BS1 = lds + 49152;
  int tid = threadIdx.x, lane = tid & 63, wid = tid >> 6;
  int wm = wid >> 2, wn = wid & 3;
  int nwg = gridDim.x;
  int id = (int)(blockIdx.x & 7) * (nwg >> 3) + (int)(blockIdx.x >> 3);
  int nC = N >> 8;
  int rowBase = (id / nC) << 8, colBase = (id % nC) << 8;

  int srow = lane >> 3;
  int scol = ((lane & 7) ^ srow) << 3;
  const unsigned short* gA = A  + (size_t)(rowBase + wid * 8 + srow) * K + scol;
  const unsigned short* gB = Bt + (size_t)(colBase + wid * 8 + srow) * K + scol;

  int r16 = lane & 15, hi = lane >> 4;
  int cxor = (lane & 7) << 4;
  int cb0 = (hi << 4) ^ cxor;
  int cb1 = (64 + (hi << 4)) ^ cxor;
  int arow = wm * 128 + r16;
  int brow = wn * 64 + r16;

  f32x4 acc[8][4] = {};
  bf16x8 a0[4][2], a1[4][2], b0[2][2], b1[2][2];

  int T = K >> 6, halfT = T >> 1;

  GL2A(AS0, 0, 0); GL2A(AS0, 0, 1);
  GL2B(BS0, 0, 0); GL2B(BS0, 0, 1);
  GL2A(AS1, 64, 0);
  asm volatile("s_waitcnt vmcnt(2)" ::: "memory");
  __builtin_amdgcn_s_barrier();

  for (int i = 0; i < halfT; ++i) {
    int e = 2 * i;
    int kE1 = (e + 1) << 6, kE2 = (e + 2) << 6, kE3 = (e + 3) << 6;
    bool s2 = (e + 2 < T), s3 = (e + 3 < T);
    READ_A4(a0, AS0, 0); READ_B2(b0, BS0, 0);
    GL2A(AS1, kE1, 1);
    PHASE_MFMA8(0, 0, a0, b0); ENDBAR();
    READ_B2(b1, BS0, 32);
    GL2B(BS1, kE1, 0);
    PHASE_MFMA8(0, 1, a0, b1); ENDBAR();
    READ_A4(a1, AS0, 64);
    GL2B(BS1, kE1, 1);
    PHASE_MFMA8(1, 0, a1, b0); ENDBAR();
    if (s2) GL2A(AS0, kE2, 0);
    PHASE_MFMA8(1, 1, a1, b1);
    if (s2) { asm volatile("s_waitcnt vmcnt(2)" ::: "memory"); }
    else    { asm volatile("s_waitcnt vmcnt(0)" ::: "memory"); }
    ENDBAR();
    READ_A4(a0, AS1, 0); READ_B2(b0, BS1, 0);
    if (s2) GL2A(AS0, kE2, 1);
    PHASE_MFMA8(0, 0, a0, b0); ENDBAR();
    READ_B2(b1, BS1, 32);
    if (s2) GL2B(BS0, kE2, 0);
    PHASE_MFMA8(0, 1, a0, b1); ENDBAR();
    READ_A4(a1, AS1, 64);
    if (s2) GL2B(BS0, kE2, 1);
    PHASE_MFMA8(1, 0, a1, b0); ENDBAR();
    if (s3) GL2A(AS1, kE3, 0);
    PHASE_MFMA8(1, 1, a1, b1);
    if (s3) { asm volatile("s_waitcnt vmcnt(2)" ::: "memory"); }
    else    { asm volatile("s_waitcnt vmcnt(0)" ::: "memory"); }
    ENDBAR();
  }

  int r0 = rowBase + wm * 128, c0 = colBase + wn * 64;
  #pragma unroll
  for (int mi = 0; mi < 8; ++mi) {
    #pragma unroll
    for (int ni = 0; ni < 4; ++ni) {
      int colg = c0 + ni * 16 + r16;
      float bsv = bias[colg];
      #pragma unroll
      for (int rr = 0; rr < 4; ++rr) {
        int rowg = r0 + mi * 16 + hi * 4 + rr;
        float v = acc[mi][ni][rr] + bsv;
        if (EPI == EPI_BF16) {
          outb[(size_t)rowg * N + colg] = f2bf(v);
        } else if (EPI == EPI_GELU) {
          outb[(size_t)rowg * N + colg] = f2bf(gelu_f(v));
        } else if (EPI == EPI_RES) {
          size_t idx = (size_t)rowg * N + colg;
          outf[idx] = v + bf2f(resid[idx]);
        } else { // EPI_PERM
          int gwin = rowg / NTW; int nn = rowg - gwin * NTW;
          int b = gwin >> 9, wd = (gwin >> 6) & 7, wh = (gwin >> 3) & 7, ww = gwin & 7;
          int dd = nn / 49; int rr2 = nn - dd * 49; int hh = rr2 / 7; int w7 = rr2 - hh * 7;
          int lflat = (wd * 2 + dd) * 3136 + (wh * 7 + hh) * 56 + (ww * 7 + w7);
          outb[(size_t)(b * LPB + lflat) * N + colg] = f2bf(v);
        }
      }
    }
  }
}

// ======================= GEMM B: 128x128 tile, 4-wave, 8-phase (round-16 verified) =======================
#define GL2A4(as_, kofs, half) do { \
  const unsigned short* ga_ = gA + (kofs) + (size_t)((half) * 64) * K; \
  gl2lds16(ga_,                  (as_) + (half) * 4096 + wid * 512); \
  gl2lds16(ga_ + (size_t)32 * K, (as_) + (half) * 4096 + 2048 + wid * 512); \
} while (0)
#define GL2B4(bs_, kofs, half) do { \
  const unsigned short* gb_ = gB + (kofs) + (size_t)((half) * 64) * K; \
  gl2lds16(gb_,                  (bs_) + (half) * 4096 + wid * 512); \
  gl2lds16(gb_ + (size_t)32 * K, (bs_) + (half) * 4096 + 2048 + wid * 512); \
} while (0)
#define READ_A2(dst, buf, mofs) { _Pragma("unroll") for (int m_ = 0; m_ < 2; ++m_) { \
    dst[m_][0] = RD16(buf, arow + (mofs) + m_ * 16, cb0); \
    dst[m_][1] = RD16(buf, arow + (mofs) + m_ * 16, cb1); } }
#define MFMA_Q4(mh, nh, av, bv) { _Pragma("unroll") for (int m_ = 0; m_ < 2; ++m_) \
  _Pragma("unroll") for (int n_ = 0; n_ < 2; ++n_) { \
    acc[(mh)*2+m_][(nh)*2+n_] = __builtin_amdgcn_mfma_f32_16x16x32_bf16(av[m_][0], bv[n_][0], acc[(mh)*2+m_][(nh)*2+n_], 0, 0, 0); \
    acc[(mh)*2+m_][(nh)*2+n_] = __builtin_amdgcn_mfma_f32_16x16x32_bf16(av[m_][1], bv[n_][1], acc[(mh)*2+m_][(nh)*2+n_], 0, 0, 0); } }
#define PHASE_MFMA4(mh, nh, av, bv) \
  __builtin_amdgcn_s_barrier(); \
  asm volatile("s_waitcnt lgkmcnt(0)" ::: "memory"); \
  __builtin_amdgcn_sched_barrier(0); \
  __builtin_amdgcn_s_setprio(1); \
  MFMA_Q4(mh, nh, av, bv); \
  __builtin_amdgcn_s_setprio(0);

template<int EPI>
__global__ __launch_bounds__(256, 2) void gemm128_kernel(
    const unsigned short* __restrict__ A,
    const unsigned short* __restrict__ Bt,
    const float* __restrict__ bias,
    unsigned short* __restrict__ outb,
    float* __restrict__ outf,
    const unsigned short* __restrict__ resid,
    int M, int N, int K) {
  extern __shared__ __attribute__((aligned(16))) unsigned short lds[];
  unsigned short* AS0 = lds;
  unsigned short* AS1 = lds + 8192;
  unsigned short* BS0 = lds + 16384;
  unsigned short* BS1 = lds + 24576;
  int tid = threadIdx.x, lane = tid & 63, wid = tid >> 6;
  int wm = wid >> 1, wn = wid & 1;
  int nwg = gridDim.x;
  int id = (int)(blockIdx.x & 7) * (nwg >> 3) + (int)(blockIdx.x >> 3);
  int nC = N >> 7;
  int rowBase = (id / nC) << 7, colBase = (id % nC) << 7;

  int srow = lane >> 3;
  int scol = ((lane & 7) ^ srow) << 3;
  const unsigned short* gA = A  + (size_t)(rowBase + wid * 8 + srow) * K + scol;
  const unsigned short* gB = Bt + (size_t)(colBase + wid * 8 + srow) * K + scol;

  int r16 = lane & 15, hi = lane >> 4;
  int cxor = (lane & 7) << 4;
  int cb0 = (hi << 4) ^ cxor;
  int cb1 = (64 + (hi << 4)) ^ cxor;
  int arow = wm * 64 + r16;
  int brow = wn * 64 + r16;

  f32x4 acc[4][4] = {};
  bf16x8 a0[2][2], a1[2][2], b0[2][2], b1[2][2];

  int T = K >> 6, halfT = T >> 1;

  GL2A4(AS0, 0, 0); GL2A4(AS0, 0, 1);
  GL2B4(BS0, 0, 0); GL2B4(BS0, 0, 1);
  GL2A4(AS1, 64, 0);
  asm volatile("s_waitcnt vmcnt(2)" ::: "memory");
  __builtin_amdgcn_s_barrier();

  for (int i = 0; i < halfT; ++i) {
    int e = 2 * i;
    int kE1 = (e + 1) << 6, kE2 = (e + 2) << 6, kE3 = (e + 3) << 6;
    bool s2 = (e + 2 < T), s3 = (e + 3 < T);
    READ_A2(a0, AS0, 0); READ_B2(b0, BS0, 0);
    GL2A4(AS1, kE1, 1);
    PHASE_MFMA4(0, 0, a0, b0); ENDBAR();
    READ_B2(b1, BS0, 32);
    GL2B4(BS1, kE1, 0);
    PHASE_MFMA4(0, 1, a0, b1); ENDBAR();
    READ_A2(a1, AS0, 32);
    GL2B4(BS1, kE1, 1);
    PHASE_MFMA4(1, 0, a1, b0); ENDBAR();
    if (s2) GL2A4(AS0, kE2, 0);
    PHASE_MFMA4(1, 1, a1, b1);
    if (s2) { asm volatile("s_waitcnt vmcnt(2)" ::: "memory"); }
    else    { asm volatile("s_waitcnt vmcnt(0)" ::: "memory"); }
    ENDBAR();
    READ_A2(a0, AS1, 0); READ_B2(b0, BS1, 0);
    if (s2) GL2A4(AS0, kE2, 1);
    PHASE_MFMA4(0, 0, a0, b0); ENDBAR();
    READ_B2(b1, BS1, 32);
    if (s2) GL2B4(BS0, kE2, 0);
    PHASE_MFMA4(0, 1, a0, b1); ENDBAR();
    READ_A2(a1, AS1, 32);
    if (s2) GL2B4(BS0, kE2, 1);
    PHASE_MFMA4(1, 0, a1, b0); ENDBAR();
    if (s3) GL2A4(AS1, kE3, 0);
    PHASE_MFMA4(1, 1, a1, b1);
    if (s3) { asm volatile("s_waitcnt vmcnt(2)" ::: "memory"); }
    else    { asm volatile("s_waitcnt vmcnt(0)" ::: "memory"); }
    ENDBAR();
  }

  int r0 = rowBase + wm * 64, c0 = colBase + wn * 64;
  #pragma unroll
  for (int mi = 0; mi < 4; ++mi) {
    #pragma unroll
    for (int ni = 0; ni < 4; ++ni) {
      int colg = c0 + ni * 16 + r16;
      float bsv = bias[colg];
      #pragma unroll
      for (int rr = 0; rr < 4; ++rr) {
        int rowg = r0 + mi * 16 + hi * 4 + rr;
        float v = acc[mi][ni][rr] + bsv;
        if (EPI == EPI_BF16) {
          outb[(size_t)rowg * N + colg] = f2bf(v);
        } else if (EPI == EPI_GELU) {
          outb[(size_t)rowg * N + colg] = f2bf(gelu_f(v));
        } else if (EPI == EPI_RES) {
          size_t idx = (size_t)rowg * N + colg;
          outf[idx] = v + bf2f(resid[idx]);
        } else { // EPI_PERM
          int gwin = rowg / NTW; int nn = rowg - gwin * NTW;
          int b = gwin >> 9, wd = (gwin >> 6) & 7, wh = (gwin >> 3) & 7, ww = gwin & 7;
          int dd = nn / 49; int rr2 = nn - dd * 49; int hh = rr2 / 7; int w7 = rr2 - hh * 7;
          int lflat = (wd * 2 + dd) * 3136 + (wh * 7 + hh) * 56 + (ww * 7 + w7);
          outb[(size_t)(b * LPB + lflat) * N + colg] = f2bf(v);
        }
      }
    }
  }
}

extern "C" void kernel_launch(void* const* d_in, const int* in_sizes, int n_in,
                              void* d_out, int out_size, void* d_ws, size_t ws_size,
                              hipStream_t stream) {
  const float* x     = (const float*)d_in[0];
  const float* g1    = (const float*)d_in[1];
  const float* b1    = (const float*)d_in[2];
  const float* wqkv  = (const float*)d_in[3];
  const float* bqkv  = (const float*)d_in[4];
  const float* wproj = (const float*)d_in[5];
  const float* bproj = (const float*)d_in[6];
  const float* g2    = (const float*)d_in[7];
  const float* b2    = (const float*)d_in[8];
  const float* w1    = (const float*)d_in[9];
  const float* bm1   = (const float*)d_in[10];
  const float* w2    = (const float*)d_in[11];
  const float* bm2   = (const float*)d_in[12];
  float* y = (float*)d_out;
  char* ws = (char*)d_ws;

  // workspace layout (bytes)
  unsigned short* wqkvT  = (unsigned short*)(ws + 0);          // 1536x512   -> 1,572,864
  unsigned short* wprojT = (unsigned short*)(ws + 1572864);    // 512x512    ->   524,288
  unsigned short* w1T    = (unsigned short*)(ws + 2097152);    // 2048x512   -> 2,097,152
  unsigned short* w2T    = (unsigned short*)(ws + 4194304);    // 512x2048   -> 2,097,152
  const size_t OFF = (size_t)8 << 20;
  const size_t ACT = (size_t)NTOK * CDIM * 2;                  // 102,760,448
  unsigned short* bufB = (unsigned short*)(ws + OFF);          // h / o / t2
  unsigned short* xr   = (unsigned short*)(ws + OFF + ACT);    // xr (bf16)
  unsigned short* bufA = (unsigned short*)(ws + OFF + 2 * ACT);// qkv / mid (max 411,041,792)
  const size_t NEEDED = OFF + 2 * ACT + (size_t)NTOK * MLPDIM * 2;
  if (ws_size < NEEDED) return;  // diagnosable: zero output, ~0 time

  const int SMEM256 = 131072;  // 128 KiB for the 256^2 GEMM
  const int SMEM128 = 65536;   // 64 KiB for the 128^2 GEMM
  (void)hipFuncSetAttribute((const void*)&gemm256_kernel<EPI_BF16>, hipFuncAttributeMaxDynamicSharedMemorySize, SMEM256);
  (void)hipFuncSetAttribute((const void*)&gemm256_kernel<EPI_PERM>, hipFuncAttributeMaxDynamicSharedMemorySize, SMEM256);
  (void)hipFuncSetAttribute((const void*)&gemm256_kernel<EPI_RES>,  hipFuncAttributeMaxDynamicSharedMemorySize, SMEM256);
  (void)hipFuncSetAttribute((const void*)&gemm128_kernel<EPI_GELU>, hipFuncAttributeMaxDynamicSharedMemorySize, SMEM128);

  // K0: weights -> bf16 transposed
  cvt_t_kernel<<<(1536 * 512 + 255) / 256, 256, 0, stream>>>(wqkv, wqkvT, 9, 1536, 1536 * 512);
  cvt_t_kernel<<<(512 * 512 + 255) / 256, 256, 0, stream>>>(wproj, wprojT, 9, 512, 512 * 512);
  cvt_t_kernel<<<(2048 * 512 + 255) / 256, 256, 0, stream>>>(w1, w1T, 9, 2048, 2048 * 512);
  cvt_t_kernel<<<(512 * 2048 + 255) / 256, 256, 0, stream>>>(w2, w2T, 11, 512, 512 * 2048);
  // K1: LN1 + partition -> h (bufB)
  ln1_kernel<<<NTOK / 4, 256, 0, stream>>>(x, g1, b1, bufB);
  // K2: QKV GEMM -> qkv (bufA)   [256^2]
  gemm256_kernel<EPI_BF16><<<(NTOK / 256) * (1536 / 256), 512, SMEM256, stream>>>(
      bufB, wqkvT, bqkv, bufA, nullptr, nullptr, NTOK, 1536, 512);
  // K3: attention -> o (bufB, h is dead)
  attn_kernel<<<(1024 * 16) / 4, 256, 0, stream>>>(bufA, bufB);
  // K4: proj GEMM + window reverse -> xr   [256^2]
  gemm256_kernel<EPI_PERM><<<(NTOK / 256) * (512 / 256), 512, SMEM256, stream>>>(
      bufB, wprojT, bproj, xr, nullptr, nullptr, NTOK, 512, 512);
  // K5a: LN2 -> t2 (bufB, o is dead)
  ln2_kernel<<<NTOK / 4, 256, 0, stream>>>(xr, g2, b2, bufB);
  // K5b: MLP1 + gelu -> mid (bufA, qkv is dead)   [128^2, measured faster for this shape]
  gemm128_kernel<EPI_GELU><<<(NTOK / 128) * (2048 / 128), 256, SMEM128, stream>>>(
      bufB, w1T, bm1, bufA, nullptr, nullptr, NTOK, 2048, 512);
  // K6: MLP2 + bias + residual -> y (fp32)   [256^2]
  gemm256_kernel<EPI_RES><<<(NTOK / 256) * (512 / 256), 512, SMEM256, stream>>>(
      bufA, w2T, bm2, nullptr, y, xr, NTOK, 512, 2048);
}